// Round 7
// baseline (551.324 us; speedup 1.0000x reference)
//
#include <hip/hip_runtime.h>

// BlockEnd: out[b,a,f] = (a < M[b]) ? relu( sum_r resid[b,a,r]*w[r,f] + node[b,a,f] ) : 0
// B=4096, A=RF=F=128. fp32 in/out; compute via bf16 MFMA (16x16x32).
//
// R5 (resubmitted R7; broker timeouts R6/R7): R4 (LDS-staged swizzled wT,
// 32-row waves) reached ~150us dispatch at 2.7 TB/s. Remaining stall found
// by code inspection: the epilogue's nd1 loads were pinned immediately after
// issue -> asm("+v") forces a vmcnt drain BEFORE the nt0 stores => a second
// serial ~900cy HBM round trip per wave. Fix: issue ALL 32 data loads (16
// resid + 16 node f32x4) in one prologue batch before __syncthreads; the
// barrier's mandatory vmcnt(0) drain covers them once, and the post-barrier
// path (cvt -> MFMA from LDS -> epilogue) has zero load stalls. Peak regs
// ~155 -> launch_bounds(256,3).

typedef __bf16 bf16x8 __attribute__((ext_vector_type(8)));
typedef float f32x4 __attribute__((ext_vector_type(4)));

static_assert(sizeof(bf16x8) == 16, "bf16x8 must be 16B");
static_assert(sizeof(f32x4) == 16, "f32x4 must be 16B");

// wTs: f-major bf16 weights, pre-swizzled so a LINEAR copy into LDS yields the
// XOR-swizzled layout: 16B unit (f, cu) holds wT_logical[f][(cu^(f&7))*8 .. +7].
__global__ __launch_bounds__(256) void wT_kernel(const float* __restrict__ w,
                                                 __bf16* __restrict__ wTs) {
    int i  = blockIdx.x * 256 + threadIdx.x;  // 0..16383 = f*128 + k
    int f  = i >> 7;
    int k  = i & 127;
    int cu = k >> 3;
    int j  = k & 7;
    int r  = ((cu ^ (f & 7)) << 3) | j;
    wTs[i] = (__bf16)w[r * 128 + f];
}

__global__ __launch_bounds__(256, 3) void blockend_kernel(
    const float* __restrict__ node,    // [B,128,128]
    const float* __restrict__ resid,   // [B,128,128]
    const __bf16* __restrict__ wTs,    // [128(f),128(r)] bf16, pre-swizzled
    const int*   __restrict__ mol,     // [B,2] int32 pairs (low word of int64)
    float*       __restrict__ out)     // [B,128,128]
{
    __shared__ __align__(16) unsigned char lds[32768];

    const int b    = blockIdx.x;       // one block per molecule
    const int t    = threadIdx.x;
    const int wave = t >> 6;
    const int lane = t & 63;
    const int quad = lane >> 4;
    const int m16  = lane & 15;

    const int M       = mol[2 * b];
    const int a_base  = wave * 32;     // 32-row wave tile
    const size_t base = (size_t)b * (128 * 128);

    // ---- stage pre-swizzled weights -> LDS: linear dest, conflict-free ----
#pragma unroll
    for (int i = 0; i < 8; ++i) {
        bf16x8 v = *(const bf16x8*)(wTs + (i * 256 + t) * 8);
        *(bf16x8*)(lds + i * 4096 + t * 16) = v;
    }

    const bool worker = (M > a_base);

    // Inactive lanes clamp their load row to wave row 0 (valid: a_base < M for
    // workers) -> duplicate reads are L1 hits, ~0 extra HBM.
    bool act0 = false, act1 = false;
    int  rr0 = 0, rr1 = 0;
    f32x4 rl[2][4], rh[2][4];
    f32x4 nd[2][8];

    if (worker) {
        act0 = (a_base + m16) < M;
        act1 = (a_base + 16 + m16) < M;
        rr0  = act0 ? m16        : 0;
        rr1  = act1 ? (16 + m16) : 0;

        const float* rowR0 = resid + base + (size_t)(a_base + rr0) * 128;
        const float* rowR1 = resid + base + (size_t)(a_base + rr1) * 128;
        const float* rowN0 = node  + base + (size_t)(a_base + rr0) * 128;
        const float* rowN1 = node  + base + (size_t)(a_base + rr1) * 128;

        // ALL 32 data loads in one batch: max MLP, single drain at the barrier.
#pragma unroll
        for (int kk = 0; kk < 4; ++kk) {
            rl[0][kk] = *(const f32x4*)(rowR0 + kk * 32 + quad * 8);
            rh[0][kk] = *(const f32x4*)(rowR0 + kk * 32 + quad * 8 + 4);
            rl[1][kk] = *(const f32x4*)(rowR1 + kk * 32 + quad * 8);
            rh[1][kk] = *(const f32x4*)(rowR1 + kk * 32 + quad * 8 + 4);
        }
#pragma unroll
        for (int ft = 0; ft < 8; ++ft) {
            nd[0][ft] = *(const f32x4*)(rowN0 + ft * 16 + quad * 4);
            nd[1][ft] = *(const f32x4*)(rowN1 + ft * 16 + quad * 4);
        }

        // Pin so no load can sink below the barrier / into the epilogue.
#pragma unroll
        for (int kk = 0; kk < 4; ++kk)
            asm volatile("" : "+v"(rl[0][kk]), "+v"(rh[0][kk]),
                              "+v"(rl[1][kk]), "+v"(rh[1][kk]));
#pragma unroll
        for (int ft = 0; ft < 8; ++ft)
            asm volatile("" : "+v"(nd[0][ft]), "+v"(nd[1][ft]));
    }

    __syncthreads();   // single vmcnt drain: staging + all 32 data loads

    float* outW = out + base + (size_t)a_base * 128;

    if (!worker) {
        // whole wave masked: 32 rows x 128 cols of zeros, coalesced float4
        f32x4 z = {0.f, 0.f, 0.f, 0.f};
        f32x4* p = (f32x4*)outW;
#pragma unroll
        for (int it = 0; it < 16; ++it)
            p[it * 64 + lane] = z;
        return;
    }

    // ---- f32 -> bf16 B-operand fragments ----
    bf16x8 rfrag[2][4];
#pragma unroll
    for (int nt = 0; nt < 2; ++nt)
#pragma unroll
        for (int kk = 0; kk < 4; ++kk) {
            bf16x8 v;
            v[0] = (__bf16)rl[nt][kk][0]; v[1] = (__bf16)rl[nt][kk][1];
            v[2] = (__bf16)rl[nt][kk][2]; v[3] = (__bf16)rl[nt][kk][3];
            v[4] = (__bf16)rh[nt][kk][0]; v[5] = (__bf16)rh[nt][kk][1];
            v[6] = (__bf16)rh[nt][kk][2]; v[7] = (__bf16)rh[nt][kk][3];
            rfrag[nt][kk] = v;
        }

    // ---- LDS read addresses (swizzled; rows r and r+8 alias = 2-way = free) ----
    const int xr = m16 & 7;
    int raddr[4];
#pragma unroll
    for (int kk = 0; kk < 4; ++kk)
        raddr[kk] = m16 * 256 + ((((kk << 2) | quad) ^ xr) << 4);

    f32x4 acc[2][8];
#pragma unroll
    for (int nt = 0; nt < 2; ++nt)
#pragma unroll
        for (int ft = 0; ft < 8; ++ft)
            acc[nt][ft] = (f32x4){0.f, 0.f, 0.f, 0.f};

    // ---- MFMA loop: wfrag from LDS, reused across both nt sub-tiles ----
#pragma unroll
    for (int ft = 0; ft < 8; ++ft) {
#pragma unroll
        for (int kk = 0; kk < 4; ++kk) {
            bf16x8 wfrag = *(const bf16x8*)(lds + ft * 4096 + raddr[kk]);
            acc[0][ft] = __builtin_amdgcn_mfma_f32_16x16x32_bf16(
                wfrag, rfrag[0][kk], acc[0][ft], 0, 0, 0);
            acc[1][ft] = __builtin_amdgcn_mfma_f32_16x16x32_bf16(
                wfrag, rfrag[1][kk], acc[1][ft], 0, 0, 0);
        }
    }

    // ---- epilogue: pure VALU + stores, everything already in registers ----
    // C layout (A=wT so m->f): f = ft*16 + quad*4 + reg, a = m16 (+ nt*16).
#pragma unroll
    for (int ft = 0; ft < 8; ++ft) {
        const int off = m16 * 128 + ft * 16 + quad * 4;
        f32x4 v;
#pragma unroll
        for (int i = 0; i < 4; ++i) {
            float x = acc[0][ft][i] + nd[0][ft][i];
            v[i] = (act0 && x > 0.f) ? x : 0.f;
        }
        *(f32x4*)(outW + off) = v;
    }
#pragma unroll
    for (int ft = 0; ft < 8; ++ft) {
        const int off = (16 + m16) * 128 + ft * 16 + quad * 4;
        f32x4 v;
#pragma unroll
        for (int i = 0; i < 4; ++i) {
            float x = acc[1][ft][i] + nd[1][ft][i];
            v[i] = (act1 && x > 0.f) ? x : 0.f;
        }
        *(f32x4*)(outW + off) = v;
    }
}

extern "C" void kernel_launch(void* const* d_in, const int* in_sizes, int n_in,
                              void* d_out, int out_size, void* d_ws, size_t ws_size,
                              hipStream_t stream) {
    const float* node  = (const float*)d_in[0];   // node_features    [4096,128,128]
    const float* resid = (const float*)d_in[1];   // residual_features[4096,128,128]
    const float* w     = (const float*)d_in[2];   // w [128,128]
    const int*   mol   = (const int*)d_in[3];     // mol_slice [4096,2] int64 -> int32 pairs
    float*       out   = (float*)d_out;
    __bf16*      wTs   = (__bf16*)d_ws;           // 32 KB scratch (pre-swizzled)

    wT_kernel<<<64, 256, 0, stream>>>(w, wTs);
    blockend_kernel<<<4096, 256, 0, stream>>>(node, resid, wTs, mol, out);
}